// Round 11
// baseline (110.746 us; speedup 1.0000x reference)
//
#include <hip/hip_runtime.h>
#include <hip/hip_bf16.h>

#define S_LEN 4096
#define QW_K  512
#define HID_N 512
#define HEADS 8
#define DH    64
// fold softmax's log2(e) into the Q pre-scale so P = exp2(s) directly
#define QSCALE (0.125f * 1.4426950408889634f)

typedef _Float16 f16;
typedef _Float16 half8  __attribute__((ext_vector_type(8)));
typedef _Float16 half4v __attribute__((ext_vector_type(4)));
typedef float    float4v __attribute__((ext_vector_type(4)));
typedef float    f32x16 __attribute__((ext_vector_type(16)));
typedef unsigned int uint;
typedef unsigned int uint4v __attribute__((ext_vector_type(4)));

__device__ inline uint pkh(float a, float b) {
    return __builtin_bit_cast(uint, __builtin_amdgcn_cvt_pkrtz(a, b)); // lo=a hi=b
}
__device__ inline void plswap(uint& a, uint& b) {
    asm volatile("v_permlane32_swap_b32 %0, %1" : "+v"(a), "+v"(b));
}
// raw hardware exp2 (TRANS pipe) — exp2f w/o fast-math lowers to OCML fixup code
__device__ inline float hexp2(float x) {
    float r;
    asm("v_exp_f32 %0, %1" : "=v"(r) : "v"(x));
    return r;
}

// ---------------------------------------------------------------------------
// Workspace layouts (r7's fragment-ordered chunks — KNOWN GOOD):
//   Q : [h][s][d]
//   Kf: [h][kt=s/32][dblk=d/16] chunk of 512 f16: (s&31)*16+((d>>3)&1)*8+(d&7)
//   Vf: [h][db=d/32][kb16=s/16] chunk of 512 f16: (d&31)*16+((s>>3)&1)*8+(s&7)
//   ctx: [s][h*64+d] f32
// Lane l = l31 + 32*g5 reads chunk offset lo = l31*16 + g5*8.
// ---------------------------------------------------------------------------

// ---------------------------------------------------------------------------
// Kernel 1: fused QKV projection.  64x128 tile, BK=64, grid (64,12) = 768
// blocks (3/CU vs 1.5 before).  Epilogue formulas identical to r7 (only the
// i-loop bound changes 4->2 since the M-tile halved).
// ---------------------------------------------------------------------------
__global__ __launch_bounds__(256) void proj_kernel(
    const float* __restrict__ xq, const float* __restrict__ xk,
    const float* __restrict__ xv, const float* __restrict__ in_proj,
    f16* __restrict__ qws, f16* __restrict__ kws, f16* __restrict__ vtws)
{
    __shared__ f16 As[64][72];
    __shared__ f16 Ws[128][72];

    const int tid  = threadIdx.x;
    const int lane = tid & 63;
    const int w    = tid >> 6;
    const int wm   = w >> 1, wn = w & 1;
    const int l15  = lane & 15, g = lane >> 4;
    const int m0   = blockIdx.x * 64;
    const int n0   = blockIdx.y * 128;
    const int matid = n0 >> 9;
    const float* A = (matid == 0) ? xq : (matid == 1) ? xk : xv;

    float4v acc[2][4];
    for (int i = 0; i < 2; i++)
        for (int j = 0; j < 4; j++)
            for (int r = 0; r < 4; r++) acc[i][j][r] = 0.0f;

    const int ar = tid >> 2;            // 0..63
    const int ac0 = (tid & 3) * 16;     // 0,16,32,48
    const int wr = tid >> 1;            // 0..127
    const int wc0 = (tid & 1) * 32;     // 0,32

    for (int k0 = 0; k0 < QW_K; k0 += 64) {
        __syncthreads();
        #pragma unroll
        for (int p = 0; p < 4; p++) {
            int c = ac0 + p * 4;
            float4v av = *(const float4v*)(A + (size_t)(m0 + ar) * QW_K + k0 + c);
            half4v ah;
            for (int e = 0; e < 4; e++) ah[e] = (f16)av[e];
            *(half4v*)&As[ar][c] = ah;
        }
        #pragma unroll
        for (int p = 0; p < 8; p++) {
            int c = wc0 + p * 4;
            float4v wv = *(const float4v*)(in_proj + (size_t)(n0 + wr) * QW_K + k0 + c);
            half4v wh;
            for (int e = 0; e < 4; e++) wh[e] = (f16)wv[e];
            *(half4v*)&Ws[wr][c] = wh;
        }
        __syncthreads();

        #pragma unroll
        for (int kk = 0; kk < 2; kk++) {
            half8 a[2], b[4];
            #pragma unroll
            for (int i = 0; i < 2; i++)
                a[i] = *(const half8*)&As[wm * 32 + i * 16 + l15][kk * 32 + g * 8];
            #pragma unroll
            for (int j = 0; j < 4; j++)
                b[j] = *(const half8*)&Ws[wn * 64 + j * 16 + l15][kk * 32 + g * 8];
            #pragma unroll
            for (int i = 0; i < 2; i++)
                #pragma unroll
                for (int j = 0; j < 4; j++)
                    acc[i][j] = __builtin_amdgcn_mfma_f32_16x16x32_f16(a[i], b[j], acc[i][j], 0, 0, 0);
        }
    }

    #pragma unroll
    for (int i = 0; i < 2; i++) {
        int grow0 = m0 + wm * 32 + i * 16 + g * 4;
        #pragma unroll
        for (int j = 0; j < 4; j++) {
            int gcol = n0 + wn * 64 + j * 16 + l15;
            int c = gcol & 511;
            int h = c >> 6, d = c & 63;
            if (matid == 2) {
                int db = d >> 5, l31v = d & 31;
                int kb16 = grow0 >> 4;
                int g5v  = (grow0 >> 3) & 1;
                int e0   = grow0 & 7;
                half4v pv;
                for (int r = 0; r < 4; r++) pv[r] = (f16)acc[i][j][r];
                *(half4v*)(vtws + ((size_t)((h * 2 + db) * 256 + kb16) << 9)
                                + l31v * 16 + g5v * 8 + e0) = pv;
            } else if (matid == 0) {
                for (int r = 0; r < 4; r++)
                    qws[((size_t)h * S_LEN + grow0 + r) * DH + d] = (f16)(acc[i][j][r] * QSCALE);
            } else {
                int dblk = d >> 4, g5k = (d >> 3) & 1, e = d & 7;
                for (int r = 0; r < 4; r++) {
                    int s = grow0 + r;
                    kws[((size_t)((h * 128 + (s >> 5)) * 4 + dblk) << 9)
                        + (s & 31) * 16 + g5k * 8 + e] = (f16)acc[i][j][r];
                }
            }
        }
    }
}

// ---------------------------------------------------------------------------
// Kernel 2: flash attention — r7 VERBATIM (passed, attn 63.5us).
// KV-split x4 with tree LDS merge.  grid = 1024 blocks x 256 thr:
// h = blk&7 (XCD pin), qb = blk>>3 (32 q-rows).  Swapped-operand 32x32x16;
// fixed-max softmax (additive partials); in-register P^T pack.
// NOTE: rounds 8-10 (512-thr 8-wave partition variants) all FAILED absmax;
// the 8-wave partition/merge structure has an unfound bug — do not retry
// without an isolation plan.
// ---------------------------------------------------------------------------
__global__ __launch_bounds__(256) void attn_kernel(
    const f16* __restrict__ qws, const f16* __restrict__ kws,
    const f16* __restrict__ vtws, float* __restrict__ ctxws)
{
    __shared__ float Ol[2][32][68];   // tree-merge buffers (17.7 KB total)
    __shared__ float Ls[2][32];

    const int tid  = threadIdx.x;
    const int lane = tid & 63;
    const int w    = tid >> 6;
    const int l31  = lane & 31;
    const int g5   = lane >> 5;
    const int blk  = blockIdx.x;
    const int h    = blk & 7;          // head == XCD (round-robin dispatch)
    const int qb   = blk >> 3;
    const int q0   = qb * 32;

    const f16* Kf = kws  + ((size_t)h * 128 * 4 << 9);
    const f16* Vf = vtws + ((size_t)h * 2 * 256 << 9);
    const int lo = l31 * 16 + g5 * 8;   // lane offset within 1KB chunk

    // Q B-fragments (col q = l31, k = d): held for the whole kernel
    half8 qf[4];
    {
        const f16* qp = qws + ((size_t)h * S_LEN + q0 + l31) * DH + g5 * 8;
        #pragma unroll
        for (int dblk = 0; dblk < 4; dblk++)
            qf[dblk] = *(const half8*)(qp + dblk * 16);
    }

    float lsum = 0.0f;
    f32x16 oacc0, oacc1;
    #pragma unroll
    for (int i = 0; i < 16; i++) { oacc0[i] = 0.0f; oacc1[i] = 0.0f; }

    const int kt0 = w * 32;            // this wave's first K 32-chunk

    // preload K fragments for iter 0
    half8 kf[2][4];
    #pragma unroll
    for (int kb32 = 0; kb32 < 2; kb32++)
        #pragma unroll
        for (int dblk = 0; dblk < 4; dblk++)
            kf[kb32][dblk] = *(const half8*)(Kf + ((size_t)((kt0 + kb32) * 4 + dblk) << 9) + lo);

    for (int t = 0; t < 16; t++) {
        const int kv0 = (w * 16 + t) * 64;

        // V fragments for this iter: 1KB coalesced chunks, issued early
        half8 vf[2][4];
        #pragma unroll
        for (int db = 0; db < 2; db++)
            #pragma unroll
            for (int kb = 0; kb < 4; kb++)
                vf[db][kb] = *(const half8*)(Vf
                    + ((size_t)((db << 8) + (kv0 >> 4) + kb) << 9) + lo);

        // QK^T (swapped): rows kv, cols q
        f32x16 st0, st1;
        #pragma unroll
        for (int i = 0; i < 16; i++) { st0[i] = 0.0f; st1[i] = 0.0f; }
        __builtin_amdgcn_s_setprio(1);
        #pragma unroll
        for (int dblk = 0; dblk < 4; dblk++) {
            st0 = __builtin_amdgcn_mfma_f32_32x32x16_f16(kf[0][dblk], qf[dblk], st0, 0, 0, 0);
            st1 = __builtin_amdgcn_mfma_f32_32x32x16_f16(kf[1][dblk], qf[dblk], st1, 0, 0, 0);
        }
        __builtin_amdgcn_s_setprio(0);

        // prefetch K for next iter (t=15 wraps to own start: harmless)
        {
            const int ktn = (t < 15) ? kt0 + t * 2 + 2 : kt0;
            #pragma unroll
            for (int kb32 = 0; kb32 < 2; kb32++)
                #pragma unroll
                for (int dblk = 0; dblk < 4; dblk++)
                    kf[kb32][dblk] = *(const half8*)(Kf
                        + ((size_t)((ktn + kb32) * 4 + dblk) << 9) + lo);
        }

        // ---- fixed-max softmax: P = exp2(st), raw v_exp_f32 ----
        #pragma unroll
        for (int i = 0; i < 16; i++) {
            st0[i] = hexp2(st0[i]);
            st1[i] = hexp2(st1[i]);
        }

        f32x16 ss;
        #pragma unroll
        for (int i = 0; i < 16; i++) ss[i] = st0[i] + st1[i];
        #pragma unroll
        for (int off = 8; off >= 1; off >>= 1)
            #pragma unroll
            for (int i = 0; i < off; i++) ss[i] += ss[i + off];
        lsum += ss[0];

        // ---- pack P^T B-fragments in-register ----
        half8 pf[4];
        #pragma unroll
        for (int kb = 0; kb < 2; kb++) {
            uint w0 = pkh(st0[8 * kb + 0], st0[8 * kb + 1]);
            uint w1 = pkh(st0[8 * kb + 2], st0[8 * kb + 3]);
            uint w2 = pkh(st0[8 * kb + 4], st0[8 * kb + 5]);
            uint w3 = pkh(st0[8 * kb + 6], st0[8 * kb + 7]);
            plswap(w0, w2);
            plswap(w1, w3);
            uint4v u; u[0] = w0; u[1] = w1; u[2] = w2; u[3] = w3;
            pf[kb] = __builtin_bit_cast(half8, u);
        }
        #pragma unroll
        for (int kb = 0; kb < 2; kb++) {
            uint w0 = pkh(st1[8 * kb + 0], st1[8 * kb + 1]);
            uint w1 = pkh(st1[8 * kb + 2], st1[8 * kb + 3]);
            uint w2 = pkh(st1[8 * kb + 4], st1[8 * kb + 5]);
            uint w3 = pkh(st1[8 * kb + 6], st1[8 * kb + 7]);
            plswap(w0, w2);
            plswap(w1, w3);
            uint4v u; u[0] = w0; u[1] = w1; u[2] = w2; u[3] = w3;
            pf[2 + kb] = __builtin_bit_cast(half8, u);
        }

        // ---- PV^T: O^T[dd][q] += V^T x P^T ----
        __builtin_amdgcn_s_setprio(1);
        #pragma unroll
        for (int kb = 0; kb < 4; kb++) {
            oacc0 = __builtin_amdgcn_mfma_f32_32x32x16_f16(vf[0][kb], pf[kb], oacc0, 0, 0, 0);
            oacc1 = __builtin_amdgcn_mfma_f32_32x32x16_f16(vf[1][kb], pf[kb], oacc1, 0, 0, 0);
        }
        __builtin_amdgcn_s_setprio(0);
    }

    // lsum finalize across the two lane-halves
    lsum += __shfl_xor(lsum, 32);

    // ---- tree merge: waves 1,3 -> LDS; 0,2 add; 2 -> LDS; 0 adds+writes ----
    if (w & 1) {
        #pragma unroll
        for (int rg = 0; rg < 4; rg++) {
            float4v v0, v1;
            #pragma unroll
            for (int j = 0; j < 4; j++) { v0[j] = oacc0[rg * 4 + j]; v1[j] = oacc1[rg * 4 + j]; }
            const int dd = rg * 8 + g5 * 4;
            *(float4v*)&Ol[w >> 1][l31][dd]      = v0;
            *(float4v*)&Ol[w >> 1][l31][32 + dd] = v1;
        }
        if (g5 == 0) Ls[w >> 1][l31] = lsum;
    }
    __syncthreads();
    if (!(w & 1)) {
        const int buf = w >> 1;
        #pragma unroll
        for (int rg = 0; rg < 4; rg++) {
            const int dd = rg * 8 + g5 * 4;
            float4v v0 = *(const float4v*)&Ol[buf][l31][dd];
            float4v v1 = *(const float4v*)&Ol[buf][l31][32 + dd];
            #pragma unroll
            for (int j = 0; j < 4; j++) { oacc0[rg * 4 + j] += v0[j]; oacc1[rg * 4 + j] += v1[j]; }
        }
        lsum += Ls[buf][l31];
    }
    __syncthreads();
    if (w == 2) {
        #pragma unroll
        for (int rg = 0; rg < 4; rg++) {
            float4v v0, v1;
            #pragma unroll
            for (int j = 0; j < 4; j++) { v0[j] = oacc0[rg * 4 + j]; v1[j] = oacc1[rg * 4 + j]; }
            const int dd = rg * 8 + g5 * 4;
            *(float4v*)&Ol[1][l31][dd]      = v0;
            *(float4v*)&Ol[1][l31][32 + dd] = v1;
        }
        if (g5 == 0) Ls[1][l31] = lsum;
    }
    __syncthreads();
    if (w == 0) {
        #pragma unroll
        for (int rg = 0; rg < 4; rg++) {
            const int dd = rg * 8 + g5 * 4;
            float4v v0 = *(const float4v*)&Ol[1][l31][dd];
            float4v v1 = *(const float4v*)&Ol[1][l31][32 + dd];
            #pragma unroll
            for (int j = 0; j < 4; j++) { oacc0[rg * 4 + j] += v0[j]; oacc1[rg * 4 + j] += v1[j]; }
        }
        lsum += Ls[1][l31];
        const float inv = 1.0f / lsum;
        float* cbase = ctxws + (size_t)(q0 + l31) * HID_N + h * DH;
        #pragma unroll
        for (int rg = 0; rg < 4; rg++) {
            float4v v0, v1;
            #pragma unroll
            for (int j = 0; j < 4; j++) {
                v0[j] = oacc0[rg * 4 + j] * inv;
                v1[j] = oacc1[rg * 4 + j] * inv;
            }
            const int dd = rg * 8 + g5 * 4;
            *(float4v*)(cbase + dd)      = v0;
            *(float4v*)(cbase + 32 + dd) = v1;
        }
    }
}

// ---------------------------------------------------------------------------
// Kernel 3: out projection.  64x128 tile, BK=64, grid (64,4) = 256 blocks.
// ctx f32 staged to f16 LDS like W.  Epilogue identical to r7 (i<2).
// ---------------------------------------------------------------------------
__global__ __launch_bounds__(256) void outproj_kernel(
    const float* __restrict__ ctxws, const float* __restrict__ w_out,
    float* __restrict__ out)
{
    __shared__ f16 As[64][72];
    __shared__ f16 Ws[128][72];

    const int tid  = threadIdx.x;
    const int lane = tid & 63;
    const int w    = tid >> 6;
    const int wm   = w >> 1, wn = w & 1;
    const int l15  = lane & 15, g = lane >> 4;
    const int m0   = blockIdx.x * 64;
    const int n0   = blockIdx.y * 128;

    float4v acc[2][4];
    for (int i = 0; i < 2; i++)
        for (int j = 0; j < 4; j++)
            for (int r = 0; r < 4; r++) acc[i][j][r] = 0.0f;

    const int ar = tid >> 2;
    const int ac0 = (tid & 3) * 16;
    const int wr = tid >> 1;
    const int wc0 = (tid & 1) * 32;

    for (int k0 = 0; k0 < HID_N; k0 += 64) {
        __syncthreads();
        #pragma unroll
        for (int p = 0; p < 4; p++) {
            int c = ac0 + p * 4;
            float4v av = *(const float4v*)(ctxws + (size_t)(m0 + ar) * HID_N + k0 + c);
            half4v ah;
            for (int e = 0; e < 4; e++) ah[e] = (f16)av[e];
            *(half4v*)&As[ar][c] = ah;
        }
        #pragma unroll
        for (int p = 0; p < 8; p++) {
            int c = wc0 + p * 4;
            float4v wv = *(const float4v*)(w_out + (size_t)(n0 + wr) * HID_N + k0 + c);
            half4v wh;
            for (int e = 0; e < 4; e++) wh[e] = (f16)wv[e];
            *(half4v*)&Ws[wr][c] = wh;
        }
        __syncthreads();

        #pragma unroll
        for (int kk = 0; kk < 2; kk++) {
            half8 a[2], b[4];
            #pragma unroll
            for (int i = 0; i < 2; i++)
                a[i] = *(const half8*)&As[wm * 32 + i * 16 + l15][kk * 32 + g * 8];
            #pragma unroll
            for (int j = 0; j < 4; j++)
                b[j] = *(const half8*)&Ws[wn * 64 + j * 16 + l15][kk * 32 + g * 8];
            #pragma unroll
            for (int i = 0; i < 2; i++)
                #pragma unroll
                for (int j = 0; j < 4; j++)
                    acc[i][j] = __builtin_amdgcn_mfma_f32_16x16x32_f16(a[i], b[j], acc[i][j], 0, 0, 0);
        }
    }

    #pragma unroll
    for (int i = 0; i < 2; i++) {
        int grow0 = m0 + wm * 32 + i * 16 + g * 4;
        #pragma unroll
        for (int j = 0; j < 4; j++) {
            int gcol = n0 + wn * 64 + j * 16 + l15;
            for (int r = 0; r < 4; r++)
                out[(size_t)(grow0 + r) * HID_N + gcol] = acc[i][j][r];
        }
    }
}

// ---------------------------------------------------------------------------
extern "C" void kernel_launch(void* const* d_in, const int* in_sizes, int n_in,
                              void* d_out, int out_size, void* d_ws, size_t ws_size,
                              hipStream_t stream)
{
    const float* xq      = (const float*)d_in[0];
    const float* xk      = (const float*)d_in[1];
    const float* xv      = (const float*)d_in[2];
    const float* in_proj = (const float*)d_in[3];
    const float* w_out   = (const float*)d_in[4];
    float* out = (float*)d_out;

    const size_t per = (size_t)HEADS * S_LEN * DH;   // 2,097,152 elems
    f16* qws   = (f16*)d_ws;
    f16* kws   = qws + per;
    f16* vtws  = kws + per;
    float* ctxws = (float*)(vtws + per);   // [4096][512] f32

    proj_kernel<<<dim3(64, 12), 256, 0, stream>>>(xq, xk, xv, in_proj, qws, kws, vtws);
    attn_kernel<<<dim3(1024), 256, 0, stream>>>(qws, kws, vtws, ctxws);
    outproj_kernel<<<dim3(64, 4), 256, 0, stream>>>(ctxws, w_out, out);
}

// Round 12
// 110.343 us; speedup vs baseline: 1.0036x; 1.0036x over previous
//
#include <hip/hip_runtime.h>
#include <hip/hip_bf16.h>

#define S_LEN 4096
#define QW_K  512
#define HID_N 512
#define HEADS 8
#define DH    64
// fold softmax's log2(e) into the Q pre-scale so P = exp2(s) directly
#define QSCALE (0.125f * 1.4426950408889634f)

typedef _Float16 f16;
typedef _Float16 half8  __attribute__((ext_vector_type(8)));
typedef _Float16 half4v __attribute__((ext_vector_type(4)));
typedef float    float4v __attribute__((ext_vector_type(4)));
typedef float    f32x16 __attribute__((ext_vector_type(16)));
typedef unsigned int uint;
typedef unsigned int uint4v __attribute__((ext_vector_type(4)));

__device__ inline uint pkh(float a, float b) {
    return __builtin_bit_cast(uint, __builtin_amdgcn_cvt_pkrtz(a, b)); // lo=a hi=b
}
__device__ inline void plswap(uint& a, uint& b) {
    asm volatile("v_permlane32_swap_b32 %0, %1" : "+v"(a), "+v"(b));
}
// raw hardware exp2 (TRANS pipe) — exp2f w/o fast-math lowers to OCML fixup code
__device__ inline float hexp2(float x) {
    float r;
    asm("v_exp_f32 %0, %1" : "=v"(r) : "v"(x));
    return r;
}
// XOR swizzle on 16B slot index within a 1KB chunk (64 slots): bijective per
// 8-slot stripe; makes both the lane-identity stage write and the fragment
// read (slot = 2*l31+g5) bank-conflict-free.
__device__ __forceinline__ int swz(int s) {
    return (s & 56) | ((s ^ (s >> 3)) & 7);
}

// ---------------------------------------------------------------------------
// Workspace layouts (r7's fragment-ordered chunks — KNOWN GOOD):
//   Q : [h][s][d]
//   Kf: [h][kt=s/32][dblk=d/16] chunk of 512 f16: (s&31)*16+((d>>3)&1)*8+(d&7)
//   Vf: [h][db=d/32][kb16=s/16] chunk of 512 f16: (d&31)*16+((s>>3)&1)*8+(s&7)
//   ctx: [s][h*64+d] f32
// Lane l = l31 + 32*g5 reads chunk offset lo = l31*16 + g5*8 (slot 2*l31+g5).
// ---------------------------------------------------------------------------

// ---------------------------------------------------------------------------
// Kernel 1: fused QKV projection (r7 verbatim, 128x128, BK=32).
// ---------------------------------------------------------------------------
__global__ __launch_bounds__(256) void proj_kernel(
    const float* __restrict__ xq, const float* __restrict__ xk,
    const float* __restrict__ xv, const float* __restrict__ in_proj,
    f16* __restrict__ qws, f16* __restrict__ kws, f16* __restrict__ vtws)
{
    __shared__ f16 As[128][40];
    __shared__ f16 Ws[128][40];

    const int tid  = threadIdx.x;
    const int lane = tid & 63;
    const int w    = tid >> 6;
    const int wm   = w >> 1, wn = w & 1;
    const int l15  = lane & 15, g = lane >> 4;
    const int m0   = blockIdx.x * 128;
    const int n0   = blockIdx.y * 128;
    const int matid = n0 >> 9;
    const float* A = (matid == 0) ? xq : (matid == 1) ? xk : xv;

    float4v acc[4][4];
    for (int i = 0; i < 4; i++)
        for (int j = 0; j < 4; j++)
            for (int r = 0; r < 4; r++) acc[i][j][r] = 0.0f;

    const int srow = tid >> 3;
    const int scol = (tid & 7) * 4;

    for (int k0 = 0; k0 < QW_K; k0 += 32) {
        __syncthreads();
        #pragma unroll
        for (int p = 0; p < 4; p++) {
            int r = p * 32 + srow;
            float4v av = *(const float4v*)(A + (size_t)(m0 + r) * QW_K + k0 + scol);
            float4v wv = *(const float4v*)(in_proj + (size_t)(n0 + r) * QW_K + k0 + scol);
            half4v ah, wh;
            for (int e = 0; e < 4; e++) { ah[e] = (f16)av[e]; wh[e] = (f16)wv[e]; }
            *(half4v*)&As[r][scol] = ah;
            *(half4v*)&Ws[r][scol] = wh;
        }
        __syncthreads();

        half8 a[4], b[4];
        #pragma unroll
        for (int i = 0; i < 4; i++) a[i] = *(const half8*)&As[wm * 64 + i * 16 + l15][g * 8];
        #pragma unroll
        for (int j = 0; j < 4; j++) b[j] = *(const half8*)&Ws[wn * 64 + j * 16 + l15][g * 8];
        #pragma unroll
        for (int i = 0; i < 4; i++)
            #pragma unroll
            for (int j = 0; j < 4; j++)
                acc[i][j] = __builtin_amdgcn_mfma_f32_16x16x32_f16(a[i], b[j], acc[i][j], 0, 0, 0);
    }

    #pragma unroll
    for (int i = 0; i < 4; i++) {
        int grow0 = m0 + wm * 64 + i * 16 + g * 4;
        #pragma unroll
        for (int j = 0; j < 4; j++) {
            int gcol = n0 + wn * 64 + j * 16 + l15;
            int c = gcol & 511;
            int h = c >> 6, d = c & 63;
            if (matid == 2) {
                int db = d >> 5, l31v = d & 31;
                int kb16 = grow0 >> 4;
                int g5v  = (grow0 >> 3) & 1;
                int e0   = grow0 & 7;
                half4v pv;
                for (int r = 0; r < 4; r++) pv[r] = (f16)acc[i][j][r];
                *(half4v*)(vtws + ((size_t)((h * 2 + db) * 256 + kb16) << 9)
                                + l31v * 16 + g5v * 8 + e0) = pv;
            } else if (matid == 0) {
                for (int r = 0; r < 4; r++)
                    qws[((size_t)h * S_LEN + grow0 + r) * DH + d] = (f16)(acc[i][j][r] * QSCALE);
            } else {
                int dblk = d >> 4, g5k = (d >> 3) & 1, e = d & 7;
                for (int r = 0; r < 4; r++) {
                    int s = grow0 + r;
                    kws[((size_t)((h * 128 + (s >> 5)) * 4 + dblk) << 9)
                        + (s & 31) * 16 + g5k * 8 + e] = (f16)acc[i][j][r];
                }
            }
        }
    }
}

// ---------------------------------------------------------------------------
// Kernel 2: flash attention — shared-KV LDS staging, NO kv-split, NO merge.
// grid = 256 blocks x 256 thr (1/CU): h = blk&7 (XCD pin), qb = blk>>3.
// 4 waves = 4 q-subblocks (32 q each); EVERY wave processes the full 4096 kv
// (64 iters of 64).  Per iter the 4 waves cooperatively stage the shared
// K+V tile (16 chunks of 1KB) into single-buffered LDS:
//   barrier -> ds_write staged regs (tile t) -> issue loads t+1 -> barrier
//   -> ds_read fragments -> QK^T -> softmax -> pack -> PV^T.
// All per-wave math/layout formulas are r7-verbatim; partial-O merge removed
// entirely (rounds 8-10's merge structure was the failing component).
// LDS slot XOR-swizzle makes stage writes AND fragment reads conflict-free.
// ---------------------------------------------------------------------------
__global__ __launch_bounds__(256) void attn_kernel(
    const f16* __restrict__ qws, const f16* __restrict__ kws,
    const f16* __restrict__ vtws, float* __restrict__ ctxws)
{
    __shared__ f16 Kl[8][512];   // [chunk][swizzled slots] 8 KB
    __shared__ f16 Vl[8][512];   // 8 KB

    const int tid  = threadIdx.x;
    const int lane = tid & 63;
    const int w    = tid >> 6;        // 0..3 = q-subblock
    const int l31  = lane & 31;
    const int g5   = lane >> 5;
    const int blk  = blockIdx.x;
    const int h    = blk & 7;         // head == XCD (round-robin dispatch)
    const int qb   = blk >> 3;        // 0..31
    const int q0   = qb * 128 + w * 32;

    const f16* Kf = kws  + (((size_t)h * 512) << 9);
    const f16* Vf = vtws + (((size_t)h * 512) << 9);
    const int swr = swz(lane) * 8;             // stage-write offset (f16)
    const int srd = swz(2 * l31 + g5) * 8;     // fragment-read offset (f16)

    // Q B-fragments (col q = l31, k = d): held for the whole kernel
    half8 qf[4];
    {
        const f16* qp = qws + ((size_t)h * S_LEN + q0 + l31) * DH + g5 * 8;
        #pragma unroll
        for (int dblk = 0; dblk < 4; dblk++)
            qf[dblk] = *(const half8*)(qp + dblk * 16);
    }

    float lsum = 0.0f;
    f32x16 oacc0, oacc1;
    #pragma unroll
    for (int i = 0; i < 16; i++) { oacc0[i] = 0.0f; oacc1[i] = 0.0f; }

    // wave w stages chunks {2w, 2w+1} of K and of V (identity copy, 16B/lane)
    const int c0 = w * 2;
    half8 kst[2], vst[2];
    #pragma unroll
    for (int i = 0; i < 2; i++) {
        const int c = c0 + i;
        kst[i] = *(const half8*)(Kf + ((size_t)(((c >> 2)) * 4 + (c & 3)) << 9) + lane * 8);
        vst[i] = *(const half8*)(Vf + ((size_t)(((c >> 2) << 8) + (c & 3)) << 9) + lane * 8);
    }

    for (int t = 0; t < 64; t++) {
        __syncthreads();   // all waves done reading tile t-1
        #pragma unroll
        for (int i = 0; i < 2; i++) {
            *(half8*)&Kl[c0 + i][swr] = kst[i];
            *(half8*)&Vl[c0 + i][swr] = vst[i];
        }
        if (t + 1 < 64) {
            const int kt = (t + 1) * 2, kb16 = (t + 1) * 4;
            #pragma unroll
            for (int i = 0; i < 2; i++) {
                const int c = c0 + i;
                kst[i] = *(const half8*)(Kf
                    + ((size_t)((kt + (c >> 2)) * 4 + (c & 3)) << 9) + lane * 8);
                vst[i] = *(const half8*)(Vf
                    + ((size_t)(((c >> 2) << 8) + kb16 + (c & 3)) << 9) + lane * 8);
            }
        }
        __syncthreads();   // tile t visible to all waves

        // fragments from LDS (r7 semantics: chunk + per-lane slot 2*l31+g5)
        half8 kf0[4], kf1[4], vf0[4], vf1[4];
        #pragma unroll
        for (int d = 0; d < 4; d++) {
            kf0[d] = *(const half8*)&Kl[d][srd];
            kf1[d] = *(const half8*)&Kl[4 + d][srd];
        }
        #pragma unroll
        for (int k = 0; k < 4; k++) {
            vf0[k] = *(const half8*)&Vl[k][srd];
            vf1[k] = *(const half8*)&Vl[4 + k][srd];
        }

        // QK^T (swapped): rows kv, cols q
        f32x16 st0, st1;
        #pragma unroll
        for (int i = 0; i < 16; i++) { st0[i] = 0.0f; st1[i] = 0.0f; }
        __builtin_amdgcn_s_setprio(1);
        #pragma unroll
        for (int dblk = 0; dblk < 4; dblk++) {
            st0 = __builtin_amdgcn_mfma_f32_32x32x16_f16(kf0[dblk], qf[dblk], st0, 0, 0, 0);
            st1 = __builtin_amdgcn_mfma_f32_32x32x16_f16(kf1[dblk], qf[dblk], st1, 0, 0, 0);
        }
        __builtin_amdgcn_s_setprio(0);

        // ---- fixed-max softmax: P = exp2(st), raw v_exp_f32 ----
        #pragma unroll
        for (int i = 0; i < 16; i++) {
            st0[i] = hexp2(st0[i]);
            st1[i] = hexp2(st1[i]);
        }

        f32x16 ss;
        #pragma unroll
        for (int i = 0; i < 16; i++) ss[i] = st0[i] + st1[i];
        #pragma unroll
        for (int off = 8; off >= 1; off >>= 1)
            #pragma unroll
            for (int i = 0; i < off; i++) ss[i] += ss[i + off];
        lsum += ss[0];

        // ---- pack P^T B-fragments in-register ----
        half8 pf[4];
        #pragma unroll
        for (int kb = 0; kb < 2; kb++) {
            uint w0 = pkh(st0[8 * kb + 0], st0[8 * kb + 1]);
            uint w1 = pkh(st0[8 * kb + 2], st0[8 * kb + 3]);
            uint w2 = pkh(st0[8 * kb + 4], st0[8 * kb + 5]);
            uint w3 = pkh(st0[8 * kb + 6], st0[8 * kb + 7]);
            plswap(w0, w2);
            plswap(w1, w3);
            uint4v u; u[0] = w0; u[1] = w1; u[2] = w2; u[3] = w3;
            pf[kb] = __builtin_bit_cast(half8, u);
        }
        #pragma unroll
        for (int kb = 0; kb < 2; kb++) {
            uint w0 = pkh(st1[8 * kb + 0], st1[8 * kb + 1]);
            uint w1 = pkh(st1[8 * kb + 2], st1[8 * kb + 3]);
            uint w2 = pkh(st1[8 * kb + 4], st1[8 * kb + 5]);
            uint w3 = pkh(st1[8 * kb + 6], st1[8 * kb + 7]);
            plswap(w0, w2);
            plswap(w1, w3);
            uint4v u; u[0] = w0; u[1] = w1; u[2] = w2; u[3] = w3;
            pf[2 + kb] = __builtin_bit_cast(half8, u);
        }

        // ---- PV^T: O^T[dd][q] += V^T x P^T ----
        __builtin_amdgcn_s_setprio(1);
        #pragma unroll
        for (int kb = 0; kb < 4; kb++) {
            oacc0 = __builtin_amdgcn_mfma_f32_32x32x16_f16(vf0[kb], pf[kb], oacc0, 0, 0, 0);
            oacc1 = __builtin_amdgcn_mfma_f32_32x32x16_f16(vf1[kb], pf[kb], oacc1, 0, 0, 0);
        }
        __builtin_amdgcn_s_setprio(0);
    }

    // lsum finalize across the two lane-halves; each wave writes its own rows
    lsum += __shfl_xor(lsum, 32);
    const float inv = 1.0f / lsum;
    float* cbase = ctxws + (size_t)(q0 + l31) * HID_N + h * DH;
    #pragma unroll
    for (int rg = 0; rg < 4; rg++) {
        float4v v0, v1;
        #pragma unroll
        for (int j = 0; j < 4; j++) {
            v0[j] = oacc0[rg * 4 + j] * inv;
            v1[j] = oacc1[rg * 4 + j] * inv;
        }
        const int dd = rg * 8 + g5 * 4;
        *(float4v*)(cbase + dd)      = v0;
        *(float4v*)(cbase + 32 + dd) = v1;
    }
}

// ---------------------------------------------------------------------------
// Kernel 3: out projection (r7 verbatim; ctx f32 staged to f16 LDS like W).
// ---------------------------------------------------------------------------
__global__ __launch_bounds__(256) void outproj_kernel(
    const float* __restrict__ ctxws, const float* __restrict__ w_out,
    float* __restrict__ out)
{
    __shared__ f16 As[128][40];
    __shared__ f16 Ws[128][40];

    const int tid  = threadIdx.x;
    const int lane = tid & 63;
    const int w    = tid >> 6;
    const int wm   = w >> 1, wn = w & 1;
    const int l15  = lane & 15, g = lane >> 4;
    const int m0   = blockIdx.x * 128;
    const int n0   = blockIdx.y * 128;

    float4v acc[4][4];
    for (int i = 0; i < 4; i++)
        for (int j = 0; j < 4; j++)
            for (int r = 0; r < 4; r++) acc[i][j][r] = 0.0f;

    const int srow = tid >> 3;
    const int scol = (tid & 7) * 4;

    for (int k0 = 0; k0 < HID_N; k0 += 32) {
        __syncthreads();
        #pragma unroll
        for (int p = 0; p < 4; p++) {
            int r = p * 32 + srow;
            float4v av = *(const float4v*)(ctxws + (size_t)(m0 + r) * HID_N + k0 + scol);
            float4v wv = *(const float4v*)(w_out + (size_t)(n0 + r) * HID_N + k0 + scol);
            half4v ah, wh;
            for (int e = 0; e < 4; e++) { ah[e] = (f16)av[e]; wh[e] = (f16)wv[e]; }
            *(half4v*)&As[r][scol] = ah;
            *(half4v*)&Ws[r][scol] = wh;
        }
        __syncthreads();

        half8 a[4], b[4];
        #pragma unroll
        for (int i = 0; i < 4; i++) a[i] = *(const half8*)&As[wm * 64 + i * 16 + l15][g * 8];
        #pragma unroll
        for (int j = 0; j < 4; j++) b[j] = *(const half8*)&Ws[wn * 64 + j * 16 + l15][g * 8];
        #pragma unroll
        for (int i = 0; i < 4; i++)
            #pragma unroll
            for (int j = 0; j < 4; j++)
                acc[i][j] = __builtin_amdgcn_mfma_f32_16x16x32_f16(a[i], b[j], acc[i][j], 0, 0, 0);
    }

    #pragma unroll
    for (int i = 0; i < 4; i++) {
        int grow0 = m0 + wm * 64 + i * 16 + g * 4;
        #pragma unroll
        for (int j = 0; j < 4; j++) {
            int gcol = n0 + wn * 64 + j * 16 + l15;
            for (int r = 0; r < 4; r++)
                out[(size_t)(grow0 + r) * HID_N + gcol] = acc[i][j][r];
        }
    }
}

// ---------------------------------------------------------------------------
extern "C" void kernel_launch(void* const* d_in, const int* in_sizes, int n_in,
                              void* d_out, int out_size, void* d_ws, size_t ws_size,
                              hipStream_t stream)
{
    const float* xq      = (const float*)d_in[0];
    const float* xk      = (const float*)d_in[1];
    const float* xv      = (const float*)d_in[2];
    const float* in_proj = (const float*)d_in[3];
    const float* w_out   = (const float*)d_in[4];
    float* out = (float*)d_out;

    const size_t per = (size_t)HEADS * S_LEN * DH;   // 2,097,152 elems
    f16* qws   = (f16*)d_ws;
    f16* kws   = qws + per;
    f16* vtws  = kws + per;
    float* ctxws = (float*)(vtws + per);   // [4096][512] f32

    proj_kernel<<<dim3(32, 12), 256, 0, stream>>>(xq, xk, xv, in_proj, qws, kws, vtws);
    attn_kernel<<<dim3(256), 256, 0, stream>>>(qws, kws, vtws, ctxws);
    outproj_kernel<<<dim3(32, 4), 256, 0, stream>>>(ctxws, w_out, out);
}

// Round 13
// 100.953 us; speedup vs baseline: 1.0970x; 1.0930x over previous
//
#include <hip/hip_runtime.h>
#include <hip/hip_bf16.h>

#define S_LEN 4096
#define QW_K  512
#define HID_N 512
#define HEADS 8
#define DH    64
// fold softmax's log2(e) into the Q pre-scale so P = exp2(s) directly
#define QSCALE (0.125f * 1.4426950408889634f)

typedef _Float16 f16;
typedef _Float16 half8  __attribute__((ext_vector_type(8)));
typedef _Float16 half4v __attribute__((ext_vector_type(4)));
typedef float    float4v __attribute__((ext_vector_type(4)));
typedef float    f32x16 __attribute__((ext_vector_type(16)));
typedef unsigned int uint;
typedef unsigned int uint4v __attribute__((ext_vector_type(4)));

__device__ inline uint pkh(float a, float b) {
    return __builtin_bit_cast(uint, __builtin_amdgcn_cvt_pkrtz(a, b)); // lo=a hi=b
}
__device__ inline void plswap(uint& a, uint& b) {
    asm volatile("v_permlane32_swap_b32 %0, %1" : "+v"(a), "+v"(b));
}
// raw hardware exp2 (TRANS pipe) — exp2f w/o fast-math lowers to OCML fixup code
__device__ inline float hexp2(float x) {
    float r;
    asm("v_exp_f32 %0, %1" : "=v"(r) : "v"(x));
    return r;
}

// ---------------------------------------------------------------------------
// Workspace layouts (r7's fragment-ordered chunks — KNOWN GOOD):
//   Q : [h][s][d]
//   Kf: [h][kt=s/32][dblk=d/16] chunk of 512 f16: (s&31)*16+((d>>3)&1)*8+(d&7)
//   Vf: [h][db=d/32][kb16=s/16] chunk of 512 f16: (d&31)*16+((s>>3)&1)*8+(s&7)
//   ctx0/ctx1: [s][h*64+d] f32 UNNORMALIZED partial O (kv half 0 / half 1)
//   L0/L1:     [s*8+h] f32 partial row sums
// Reader lane l = l31 + 32*g5 needs chunk 16B-slot g(l) = 2*l31 + g5.
// LDS staging stores global slot g(l) AT slot l (write permutation
// p(lane) = (lane&1)*32 + (lane>>1), 2-way bank alias = free) so fragment
// reads are slot = lane: perfectly linear, conflict-free.
// ---------------------------------------------------------------------------

// ---------------------------------------------------------------------------
// Kernel 1: fused QKV projection (r7 verbatim, 128x128, BK=32).
// ---------------------------------------------------------------------------
__global__ __launch_bounds__(256) void proj_kernel(
    const float* __restrict__ xq, const float* __restrict__ xk,
    const float* __restrict__ xv, const float* __restrict__ in_proj,
    f16* __restrict__ qws, f16* __restrict__ kws, f16* __restrict__ vtws)
{
    __shared__ f16 As[128][40];
    __shared__ f16 Ws[128][40];

    const int tid  = threadIdx.x;
    const int lane = tid & 63;
    const int w    = tid >> 6;
    const int wm   = w >> 1, wn = w & 1;
    const int l15  = lane & 15, g = lane >> 4;
    const int m0   = blockIdx.x * 128;
    const int n0   = blockIdx.y * 128;
    const int matid = n0 >> 9;
    const float* A = (matid == 0) ? xq : (matid == 1) ? xk : xv;

    float4v acc[4][4];
    for (int i = 0; i < 4; i++)
        for (int j = 0; j < 4; j++)
            for (int r = 0; r < 4; r++) acc[i][j][r] = 0.0f;

    const int srow = tid >> 3;
    const int scol = (tid & 7) * 4;

    for (int k0 = 0; k0 < QW_K; k0 += 32) {
        __syncthreads();
        #pragma unroll
        for (int p = 0; p < 4; p++) {
            int r = p * 32 + srow;
            float4v av = *(const float4v*)(A + (size_t)(m0 + r) * QW_K + k0 + scol);
            float4v wv = *(const float4v*)(in_proj + (size_t)(n0 + r) * QW_K + k0 + scol);
            half4v ah, wh;
            for (int e = 0; e < 4; e++) { ah[e] = (f16)av[e]; wh[e] = (f16)wv[e]; }
            *(half4v*)&As[r][scol] = ah;
            *(half4v*)&Ws[r][scol] = wh;
        }
        __syncthreads();

        half8 a[4], b[4];
        #pragma unroll
        for (int i = 0; i < 4; i++) a[i] = *(const half8*)&As[wm * 64 + i * 16 + l15][g * 8];
        #pragma unroll
        for (int j = 0; j < 4; j++) b[j] = *(const half8*)&Ws[wn * 64 + j * 16 + l15][g * 8];
        #pragma unroll
        for (int i = 0; i < 4; i++)
            #pragma unroll
            for (int j = 0; j < 4; j++)
                acc[i][j] = __builtin_amdgcn_mfma_f32_16x16x32_f16(a[i], b[j], acc[i][j], 0, 0, 0);
    }

    #pragma unroll
    for (int i = 0; i < 4; i++) {
        int grow0 = m0 + wm * 64 + i * 16 + g * 4;
        #pragma unroll
        for (int j = 0; j < 4; j++) {
            int gcol = n0 + wn * 64 + j * 16 + l15;
            int c = gcol & 511;
            int h = c >> 6, d = c & 63;
            if (matid == 2) {
                int db = d >> 5, l31v = d & 31;
                int kb16 = grow0 >> 4;
                int g5v  = (grow0 >> 3) & 1;
                int e0   = grow0 & 7;
                half4v pv;
                for (int r = 0; r < 4; r++) pv[r] = (f16)acc[i][j][r];
                *(half4v*)(vtws + ((size_t)((h * 2 + db) * 256 + kb16) << 9)
                                + l31v * 16 + g5v * 8 + e0) = pv;
            } else if (matid == 0) {
                for (int r = 0; r < 4; r++)
                    qws[((size_t)h * S_LEN + grow0 + r) * DH + d] = (f16)(acc[i][j][r] * QSCALE);
            } else {
                int dblk = d >> 4, g5k = (d >> 3) & 1, e = d & 7;
                for (int r = 0; r < 4; r++) {
                    int s = grow0 + r;
                    kws[((size_t)((h * 128 + (s >> 5)) * 4 + dblk) << 9)
                        + (s & 31) * 16 + g5k * 8 + e] = (f16)acc[i][j][r];
                }
            }
        }
    }
}

// ---------------------------------------------------------------------------
// Kernel 2: flash attention — shared-KV within block (r12-proven structure),
// kv-split ACROSS blocks, merge via dual output buffers (no cross-wave merge).
// grid = 512 x 256 thr: kvh = blk>>8, h = blk&7 (XCD pin), qb = (blk>>3)&31.
// 4 waves = 4 q-subblocks (32 q each); block processes its 2048-kv half
// (32 iters of 64), staging each shared 16KB K+V tile into LDS.
// Writes UNNORMALIZED O^T partials to ctx0/ctx1 and row sums to L0/L1;
// outproj performs the additive merge + normalization.
// 172 regs -> 2 waves/SIMD at 2 blocks/CU; stage-write permuted (2-way free),
// fragment reads slot=lane (conflict-free).
// ---------------------------------------------------------------------------
__global__ __launch_bounds__(256) void attn_kernel(
    const f16* __restrict__ qws, const f16* __restrict__ kws,
    const f16* __restrict__ vtws, float* __restrict__ ctx0,
    float* __restrict__ ctx1, float* __restrict__ L0, float* __restrict__ L1)
{
    __shared__ f16 Kl[8][512];   // [chunk][16B slots, slot l = reader lane l]
    __shared__ f16 Vl[8][512];

    const int tid  = threadIdx.x;
    const int lane = tid & 63;
    const int w    = tid >> 6;        // 0..3 = q-subblock
    const int l31  = lane & 31;
    const int g5   = lane >> 5;
    const int blk  = blockIdx.x;
    const int kvh  = blk >> 8;        // kv half
    const int h    = blk & 7;         // head == XCD (round-robin dispatch)
    const int qb   = (blk >> 3) & 31;
    const int q0   = qb * 128 + w * 32;

    const f16* Kf = kws  + (((size_t)h * 512) << 9);
    const f16* Vf = vtws + (((size_t)h * 512) << 9);
    const int pw = ((lane & 1) * 32 + (lane >> 1)) * 8;  // stage-write offset

    // Q B-fragments (col q = l31, k = d): held for the whole kernel
    half8 qf[4];
    {
        const f16* qp = qws + ((size_t)h * S_LEN + q0 + l31) * DH + g5 * 8;
        #pragma unroll
        for (int dblk = 0; dblk < 4; dblk++)
            qf[dblk] = *(const half8*)(qp + dblk * 16);
    }

    float lsum = 0.0f;
    f32x16 oacc0, oacc1;
    #pragma unroll
    for (int i = 0; i < 16; i++) { oacc0[i] = 0.0f; oacc1[i] = 0.0f; }

    // wave w stages chunks {2w, 2w+1} of K and V (16B/lane identity copy)
    const int c0 = w * 2;
    const int T0 = kvh * 32;          // first kv tile of this block's half
    half8 kst[2], vst[2];
    #pragma unroll
    for (int i = 0; i < 2; i++) {
        const int c = c0 + i;
        kst[i] = *(const half8*)(Kf
            + ((size_t)((T0 * 2 + (c >> 2)) * 4 + (c & 3)) << 9) + lane * 8);
        vst[i] = *(const half8*)(Vf
            + ((size_t)(((c >> 2) << 8) + T0 * 4 + (c & 3)) << 9) + lane * 8);
    }

    for (int t = 0; t < 32; t++) {
        __syncthreads();   // all waves done reading tile t-1
        #pragma unroll
        for (int i = 0; i < 2; i++) {
            *(half8*)&Kl[c0 + i][pw] = kst[i];
            *(half8*)&Vl[c0 + i][pw] = vst[i];
        }
        if (t + 1 < 32) {
            const int T = T0 + t + 1;
            #pragma unroll
            for (int i = 0; i < 2; i++) {
                const int c = c0 + i;
                kst[i] = *(const half8*)(Kf
                    + ((size_t)((T * 2 + (c >> 2)) * 4 + (c & 3)) << 9) + lane * 8);
                vst[i] = *(const half8*)(Vf
                    + ((size_t)(((c >> 2) << 8) + T * 4 + (c & 3)) << 9) + lane * 8);
            }
        }
        __syncthreads();   // tile t visible to all waves

        // fragments from LDS: slot = lane (linear, conflict-free)
        half8 kf0[4], kf1[4], vf0[4], vf1[4];
        #pragma unroll
        for (int d = 0; d < 4; d++) {
            kf0[d] = *(const half8*)&Kl[d][lane * 8];
            kf1[d] = *(const half8*)&Kl[4 + d][lane * 8];
        }
        #pragma unroll
        for (int k = 0; k < 4; k++) {
            vf0[k] = *(const half8*)&Vl[k][lane * 8];
            vf1[k] = *(const half8*)&Vl[4 + k][lane * 8];
        }

        // QK^T (swapped): rows kv, cols q
        f32x16 st0, st1;
        #pragma unroll
        for (int i = 0; i < 16; i++) { st0[i] = 0.0f; st1[i] = 0.0f; }
        __builtin_amdgcn_s_setprio(1);
        #pragma unroll
        for (int dblk = 0; dblk < 4; dblk++) {
            st0 = __builtin_amdgcn_mfma_f32_32x32x16_f16(kf0[dblk], qf[dblk], st0, 0, 0, 0);
            st1 = __builtin_amdgcn_mfma_f32_32x32x16_f16(kf1[dblk], qf[dblk], st1, 0, 0, 0);
        }
        __builtin_amdgcn_s_setprio(0);

        // ---- fixed-max softmax: P = exp2(st), raw v_exp_f32 ----
        #pragma unroll
        for (int i = 0; i < 16; i++) {
            st0[i] = hexp2(st0[i]);
            st1[i] = hexp2(st1[i]);
        }

        f32x16 ss;
        #pragma unroll
        for (int i = 0; i < 16; i++) ss[i] = st0[i] + st1[i];
        #pragma unroll
        for (int off = 8; off >= 1; off >>= 1)
            #pragma unroll
            for (int i = 0; i < off; i++) ss[i] += ss[i + off];
        lsum += ss[0];

        // ---- pack P^T B-fragments in-register ----
        half8 pf[4];
        #pragma unroll
        for (int kb = 0; kb < 2; kb++) {
            uint w0 = pkh(st0[8 * kb + 0], st0[8 * kb + 1]);
            uint w1 = pkh(st0[8 * kb + 2], st0[8 * kb + 3]);
            uint w2 = pkh(st0[8 * kb + 4], st0[8 * kb + 5]);
            uint w3 = pkh(st0[8 * kb + 6], st0[8 * kb + 7]);
            plswap(w0, w2);
            plswap(w1, w3);
            uint4v u; u[0] = w0; u[1] = w1; u[2] = w2; u[3] = w3;
            pf[kb] = __builtin_bit_cast(half8, u);
        }
        #pragma unroll
        for (int kb = 0; kb < 2; kb++) {
            uint w0 = pkh(st1[8 * kb + 0], st1[8 * kb + 1]);
            uint w1 = pkh(st1[8 * kb + 2], st1[8 * kb + 3]);
            uint w2 = pkh(st1[8 * kb + 4], st1[8 * kb + 5]);
            uint w3 = pkh(st1[8 * kb + 6], st1[8 * kb + 7]);
            plswap(w0, w2);
            plswap(w1, w3);
            uint4v u; u[0] = w0; u[1] = w1; u[2] = w2; u[3] = w3;
            pf[2 + kb] = __builtin_bit_cast(half8, u);
        }

        // ---- PV^T: O^T[dd][q] += V^T x P^T ----
        __builtin_amdgcn_s_setprio(1);
        #pragma unroll
        for (int kb = 0; kb < 4; kb++) {
            oacc0 = __builtin_amdgcn_mfma_f32_32x32x16_f16(vf0[kb], pf[kb], oacc0, 0, 0, 0);
            oacc1 = __builtin_amdgcn_mfma_f32_32x32x16_f16(vf1[kb], pf[kb], oacc1, 0, 0, 0);
        }
        __builtin_amdgcn_s_setprio(0);
    }

    // lsum finalize across the two lane-halves; write UNNORMALIZED partials
    lsum += __shfl_xor(lsum, 32);
    float* cx = kvh ? ctx1 : ctx0;
    float* Lx = kvh ? L1 : L0;
    float* cbase = cx + (size_t)(q0 + l31) * HID_N + h * DH;
    #pragma unroll
    for (int rg = 0; rg < 4; rg++) {
        float4v v0, v1;
        #pragma unroll
        for (int j = 0; j < 4; j++) {
            v0[j] = oacc0[rg * 4 + j];
            v1[j] = oacc1[rg * 4 + j];
        }
        const int dd = rg * 8 + g5 * 4;
        *(float4v*)(cbase + dd)      = v0;
        *(float4v*)(cbase + 32 + dd) = v1;
    }
    if (g5 == 0) Lx[(q0 + l31) * 8 + h] = lsum;
}

// ---------------------------------------------------------------------------
// Kernel 3: out projection + attention merge.  Stages
// (ctx0+ctx1) * 1/(L0+L1) to f16 LDS, then r7's proven 128x128 MFMA GEMM.
// ---------------------------------------------------------------------------
__global__ __launch_bounds__(256) void outproj_kernel(
    const float* __restrict__ ctx0, const float* __restrict__ ctx1,
    const float* __restrict__ L0, const float* __restrict__ L1,
    const float* __restrict__ w_out, float* __restrict__ out)
{
    __shared__ f16 As[128][40];
    __shared__ f16 Ws[128][40];

    const int tid  = threadIdx.x;
    const int lane = tid & 63;
    const int w    = tid >> 6;
    const int wm   = w >> 1, wn = w & 1;
    const int l15  = lane & 15, g = lane >> 4;
    const int m0   = blockIdx.x * 128;
    const int n0   = blockIdx.y * 128;

    float4v acc[4][4];
    for (int i = 0; i < 4; i++)
        for (int j = 0; j < 4; j++)
            for (int r = 0; r < 4; r++) acc[i][j][r] = 0.0f;

    const int srow = tid >> 3;
    const int scol = (tid & 7) * 4;

    for (int k0 = 0; k0 < HID_N; k0 += 32) {
        __syncthreads();
        const int hh = (k0 + scol) >> 6;   // head of this thread's quad
        #pragma unroll
        for (int p = 0; p < 4; p++) {
            int r = p * 32 + srow;
            int s = m0 + r;
            float4v a0 = *(const float4v*)(ctx0 + (size_t)s * HID_N + k0 + scol);
            float4v a1 = *(const float4v*)(ctx1 + (size_t)s * HID_N + k0 + scol);
            float inv = 1.0f / (L0[s * 8 + hh] + L1[s * 8 + hh]);
            float4v wv = *(const float4v*)(w_out + (size_t)(n0 + r) * HID_N + k0 + scol);
            half4v ah, wh;
            for (int e = 0; e < 4; e++) {
                ah[e] = (f16)((a0[e] + a1[e]) * inv);
                wh[e] = (f16)wv[e];
            }
            *(half4v*)&As[r][scol] = ah;
            *(half4v*)&Ws[r][scol] = wh;
        }
        __syncthreads();

        half8 a[4], b[4];
        #pragma unroll
        for (int i = 0; i < 4; i++) a[i] = *(const half8*)&As[wm * 64 + i * 16 + l15][g * 8];
        #pragma unroll
        for (int j = 0; j < 4; j++) b[j] = *(const half8*)&Ws[wn * 64 + j * 16 + l15][g * 8];
        #pragma unroll
        for (int i = 0; i < 4; i++)
            #pragma unroll
            for (int j = 0; j < 4; j++)
                acc[i][j] = __builtin_amdgcn_mfma_f32_16x16x32_f16(a[i], b[j], acc[i][j], 0, 0, 0);
    }

    #pragma unroll
    for (int i = 0; i < 4; i++) {
        int grow0 = m0 + wm * 64 + i * 16 + g * 4;
        #pragma unroll
        for (int j = 0; j < 4; j++) {
            int gcol = n0 + wn * 64 + j * 16 + l15;
            for (int r = 0; r < 4; r++)
                out[(size_t)(grow0 + r) * HID_N + gcol] = acc[i][j][r];
        }
    }
}

// ---------------------------------------------------------------------------
extern "C" void kernel_launch(void* const* d_in, const int* in_sizes, int n_in,
                              void* d_out, int out_size, void* d_ws, size_t ws_size,
                              hipStream_t stream)
{
    const float* xq      = (const float*)d_in[0];
    const float* xk      = (const float*)d_in[1];
    const float* xv      = (const float*)d_in[2];
    const float* in_proj = (const float*)d_in[3];
    const float* w_out   = (const float*)d_in[4];
    float* out = (float*)d_out;

    const size_t per = (size_t)HEADS * S_LEN * DH;   // 2,097,152 elems
    f16* qws   = (f16*)d_ws;
    f16* kws   = qws + per;
    f16* vtws  = kws + per;
    float* ctx0 = (float*)(vtws + per);              // [4096][512] f32
    float* ctx1 = ctx0 + (size_t)S_LEN * HID_N;
    float* L0   = ctx1 + (size_t)S_LEN * HID_N;      // [4096*8]
    float* L1   = L0 + (size_t)S_LEN * HEADS;

    proj_kernel<<<dim3(32, 12), 256, 0, stream>>>(xq, xk, xv, in_proj, qws, kws, vtws);
    attn_kernel<<<dim3(512), 256, 0, stream>>>(qws, kws, vtws, ctx0, ctx1, L0, L1);
    outproj_kernel<<<dim3(32, 4), 256, 0, stream>>>(ctx0, ctx1, L0, L1, w_out, out);
}